// Round 19
// baseline (255.925 us; speedup 1.0000x reference)
//
#include <hip/hip_runtime.h>
#include <cmath>

#define NN 20000
#define NE 320000
#define TT 8
#define EPSF 1e-16f
#define NR 32          // dst ranges per timestep
#define RSZ 625        // NN / NR
#define NCH 1250       // edge chunks per timestep (256 edges each)

// ---- workspace layout (4-byte word offsets) ----
#define OFF_RT  0                        // int [T][NR] range totals (1024 pad)
#define OFF_ROW 1024                     // int [T][N+1] CSR row starts
#define OFF_CSR (OFF_ROW + TT*(NN+1))    // ushort[T][NE]
#define OFF_H2S (OFF_CSR + TT*NE/2)      // float [T][N][32]  (aliases bh)
#define OFF_AS2 (OFF_H2S + TT*NN*32)     // float [T][N]
#define OFF_AD2 (OFF_AS2 + TT*NN)        // float [T][N]
#define OFF_ENC (OFF_AD2 + TT*NN)        // float [T][N][32]  (aliases bkt)
#define OFF_WP  (OFF_ENC + TT*NN*32)     // packed GRU weights
#define WS_WORDS (OFF_WP + 6144)

__device__ __forceinline__ float fexp(float x) { return __expf(x); }
__device__ __forceinline__ float fsigmoid(float x) { return 1.f / (1.f + __expf(-x)); }
__device__ __forceinline__ float ftanh(float x) {
    float ax = fabsf(x);
    float e2 = __expf(-2.f * ax);
    float th = (1.f - e2) / (1.f + e2);
    return copysignf(th, x);
}

// Stage 1: per-(t,chunk) histogram over NR dst ranges. 1 edge per thread.
// Blocks 0..3 additionally pack the GRU weights into wp:
//   wp[0..4096)  float4 {wi_r, wi_z, wi_n, wh_r}[k*32+j]
//   wp[4096..)   float2 {wh_z, wh_n}[k*32+j]
__global__ __launch_bounds__(256) void k_bhist(const int* __restrict__ ei,
                                               int* __restrict__ bh,
                                               const float* __restrict__ wih,
                                               const float* __restrict__ whh,
                                               float* __restrict__ wp) {
    int b = blockIdx.x;
    int t = b & 7, c = b >> 3;
    __shared__ int cnt[NR];
    int tid = threadIdx.x;
    if (b < 4) {                       // fold k_wpack: 4*256 = 1024 entries
        int i = b * 256 + tid;
        int k = i >> 5, j = i & 31;
        ((float4*)wp)[i] = make_float4(wih[j * 32 + k], wih[(32 + j) * 32 + k],
                                       wih[(64 + j) * 32 + k], whh[j * 32 + k]);
        ((float2*)(wp + 4096))[i] = make_float2(whh[(32 + j) * 32 + k],
                                                whh[(64 + j) * 32 + k]);
    }
    if (tid < NR) cnt[tid] = 0;
    __syncthreads();
    int e = c * 256 + tid;
    int dst = ei[(size_t)t * 2 * NE + NE + e];
    int r = dst / RSZ;
    atomicAdd(&cnt[r], 1);
    __syncthreads();
    if (tid < NR) bh[(t * NCH + c) * NR + tid] = cnt[tid];
}

// Stage 2: per-(t,r) exclusive scan over NCH chunk counts (in place) + totals.
__global__ __launch_bounds__(256) void k_bscan1(int* __restrict__ bh,
                                                int* __restrict__ rt) {
    int b = blockIdx.x;                // 256 = (t,r)
    int t = b & 7, r = b >> 3;
    __shared__ int sums[256];
    int tid = threadIdx.x;
    int c0 = tid * 5, c1 = c0 + 5; if (c1 > NCH) c1 = NCH; if (c0 > NCH) c0 = NCH;
    int v[5]; int s = 0;
    for (int c = c0, k = 0; c < c1; c++, k++) { v[k] = bh[(t * NCH + c) * NR + r]; s += v[k]; }
    sums[tid] = s;
    __syncthreads();
    if (tid == 0) {
        int acc = 0;
        for (int i = 0; i < 256; i++) { int x = sums[i]; sums[i] = acc; acc += x; }
        rt[t * NR + r] = acc;          // bucket total
    }
    __syncthreads();
    int acc = sums[tid];
    for (int c = c0, k = 0; c < c1; c++, k++) { bh[(t * NCH + c) * NR + r] = acc; acc += v[k]; }
}

// Stage 3: place each edge into its range bucket. bkt entry: (src<<10)|dstlocal.
__global__ __launch_bounds__(256) void k_bplace(const int* __restrict__ ei,
                                                const int* __restrict__ bh,
                                                const int* __restrict__ rt,
                                                unsigned* __restrict__ bkt) {
    int b = blockIdx.x;
    int t = b & 7, c = b >> 3;
    __shared__ int cnt[NR], base[NR], rbs[NR];
    int tid = threadIdx.x;
    if (tid == 0) {
        int acc = 0;
        for (int r = 0; r < NR; r++) { rbs[r] = acc; acc += rt[t * NR + r]; }
    }
    if (tid < NR) {
        cnt[tid] = 0;
        base[tid] = bh[(t * NCH + c) * NR + tid];
    }
    __syncthreads();
    int e = c * 256 + tid;
    int src = ei[(size_t)t * 2 * NE + e];
    int dst = ei[(size_t)t * 2 * NE + NE + e];
    int r = dst / RSZ;
    int pos = atomicAdd(&cnt[r], 1);
    bkt[(size_t)t * NE + rbs[r] + base[r] + pos] =
        ((unsigned)src << 10) | (unsigned)(dst - r * RSZ);
}

// Stage 4: per-(t,r) bucket -> per-dst CSR. Each block owns ~10K edges.
__global__ __launch_bounds__(256) void k_csr(const unsigned* __restrict__ bkt,
                                             const int* __restrict__ rt,
                                             int* __restrict__ row,
                                             unsigned short* __restrict__ csr) {
    int b = blockIdx.x;                // 256 = (t,r)
    int t = b & 7, r = b >> 3;
    __shared__ int segs[2];
    __shared__ int deg[RSZ];
    __shared__ int cur[RSZ];
    __shared__ int sums[256];
    int tid = threadIdx.x;
    if (tid == 0) {
        int acc = 0, s0 = 0;
        for (int i = 0; i < NR; i++) { if (i == r) s0 = acc; acc += rt[t * NR + i]; }
        segs[0] = s0;
        segs[1] = (r == NR - 1) ? acc : s0 + rt[t * NR + r];
    }
    for (int i = tid; i < RSZ; i += 256) deg[i] = 0;
    __syncthreads();
    int seg0 = segs[0], seg1 = segs[1];
    int lo = r * RSZ;
    const unsigned* bp = bkt + (size_t)t * NE;
    for (int i = seg0 + tid; i < seg1; i += 256)
        atomicAdd(&deg[bp[i] & 1023], 1);
    __syncthreads();
    int c0 = tid * 3, c1 = c0 + 3; if (c1 > RSZ) c1 = RSZ; if (c0 > RSZ) c0 = RSZ;
    int v[3]; int s = 0;
    for (int i = c0, k = 0; i < c1; i++, k++) { v[k] = deg[i]; s += v[k]; }
    sums[tid] = s;
    __syncthreads();
    if (tid == 0) {
        int acc = 0;
        for (int i = 0; i < 256; i++) { int x = sums[i]; sums[i] = acc; acc += x; }
    }
    __syncthreads();
    int acc = sums[tid];
    for (int i = c0, k = 0; i < c1; i++, k++) {
        int off = seg0 + acc;
        row[t * (NN + 1) + lo + i] = off;
        cur[i] = off;
        acc += v[k];
    }
    if (r == NR - 1 && tid == 0) row[t * (NN + 1) + NN] = seg1;  // == NE
    __syncthreads();
    unsigned short* cp = csr + (size_t)t * NE;
    for (int i = seg0 + tid; i < seg1; i += 256) {
        unsigned pk = bp[i];
        int pos = atomicAdd(&cur[pk & 1023], 1);
        cp[pos] = (unsigned short)(pk >> 10);
    }
}

// Fused: layer-1 scalar-softmax gather + h1 -> h2 matvec + layer-2 attn scalars
__global__ __launch_bounds__(256) void k_l1(
        const float* __restrict__ x, const int* __restrict__ row,
        const unsigned short* __restrict__ csr,
        const float* __restrict__ as1, const float* __restrict__ ad1,
        const float* __restrict__ W1, const float* __restrict__ b1,
        const float* __restrict__ W2,
        const float* __restrict__ as2w, const float* __restrict__ ad2w,
        float* __restrict__ h2s, float* __restrict__ as2, float* __restrict__ ad2) {
    __shared__ float sW2[64 * 32];
    __shared__ float sW1[64], sb1[64], sas[32], sad[32], sc[4];
    int tid = threadIdx.x;
    for (int i = tid; i < 64 * 32; i += 256) sW2[i] = W2[i];
    if (tid < 64) { sW1[tid] = W1[tid]; sb1[tid] = b1[tid]; }
    if (tid < 32) { sas[tid] = as2w[tid]; sad[tid] = ad2w[tid]; }
    if (tid < 4) {                      // sc = {cs1_h0, cs1_h1, cd1_h0, cd1_h1}
        int hd = tid & 1;
        const float* att = (tid < 2) ? as1 : ad1;
        float s = 0.f;
        for (int k = 0; k < 32; k++) s += W1[hd * 32 + k] * att[hd * 32 + k];
        sc[tid] = s;
    }
    __syncthreads();
    int b = blockIdx.x;
    int t = b & 7, chunk = b >> 3;      // 79 chunks per t
    int n = chunk * 256 + tid;
    if (n >= NN) return;
    int idx = t * NN + n;
    float cs0 = sc[0], cs1 = sc[1], cd0 = sc[2], cd1 = sc[3];
    float xd = x[idx];
    // self-loop term (src == dst == n)
    float v0 = xd * (cs0 + cd0); v0 = v0 > 0.f ? v0 : 0.2f * v0; float ex0 = fexp(v0);
    float v1 = xd * (cs1 + cd1); v1 = v1 > 0.f ? v1 : 0.2f * v1; float ex1 = fexp(v1);
    float den0 = ex0, den1 = ex1, S0 = ex0 * xd, S1 = ex1 * xd;
    int rs = row[t * (NN + 1) + n], re = row[t * (NN + 1) + n + 1];
    const unsigned short* cp = csr + (size_t)t * NE;
    const float* xp = x + t * NN;
    int i = rs;
    for (; i < re && (i & 3); i++) {
        int src = cp[i];
        float xs = xp[src];
        float u0 = xs * cs0 + xd * cd0; u0 = u0 > 0.f ? u0 : 0.2f * u0; float q0 = fexp(u0);
        float u1 = xs * cs1 + xd * cd1; u1 = u1 > 0.f ? u1 : 0.2f * u1; float q1 = fexp(u1);
        den0 += q0; S0 += q0 * xs;
        den1 += q1; S1 += q1 * xs;
    }
    for (; i + 4 <= re; i += 4) {
        ushort4 s4 = *(const ushort4*)(cp + i);    // 8B aligned: i%4==0
        float xA = xp[s4.x], xB = xp[s4.y], xC = xp[s4.z], xD = xp[s4.w];
        float uA0 = xA * cs0 + xd * cd0; uA0 = uA0 > 0.f ? uA0 : 0.2f * uA0; float qA0 = fexp(uA0);
        float uB0 = xB * cs0 + xd * cd0; uB0 = uB0 > 0.f ? uB0 : 0.2f * uB0; float qB0 = fexp(uB0);
        float uC0 = xC * cs0 + xd * cd0; uC0 = uC0 > 0.f ? uC0 : 0.2f * uC0; float qC0 = fexp(uC0);
        float uD0 = xD * cs0 + xd * cd0; uD0 = uD0 > 0.f ? uD0 : 0.2f * uD0; float qD0 = fexp(uD0);
        float uA1 = xA * cs1 + xd * cd1; uA1 = uA1 > 0.f ? uA1 : 0.2f * uA1; float qA1 = fexp(uA1);
        float uB1 = xB * cs1 + xd * cd1; uB1 = uB1 > 0.f ? uB1 : 0.2f * uB1; float qB1 = fexp(uB1);
        float uC1 = xC * cs1 + xd * cd1; uC1 = uC1 > 0.f ? uC1 : 0.2f * uC1; float qC1 = fexp(uC1);
        float uD1 = xD * cs1 + xd * cd1; uD1 = uD1 > 0.f ? uD1 : 0.2f * uD1; float qD1 = fexp(uD1);
        den0 += (qA0 + qB0) + (qC0 + qD0);
        S0 += qA0 * xA + qB0 * xB + qC0 * xC + qD0 * xD;
        den1 += (qA1 + qB1) + (qC1 + qD1);
        S1 += qA1 * xA + qB1 * xB + qC1 * xC + qD1 * xD;
    }
    for (; i < re; i++) {
        int src = cp[i];
        float xs = xp[src];
        float u0 = xs * cs0 + xd * cd0; u0 = u0 > 0.f ? u0 : 0.2f * u0; float q0 = fexp(u0);
        float u1 = xs * cs1 + xd * cd1; u1 = u1 > 0.f ? u1 : 0.2f * u1; float q1 = fexp(u1);
        den0 += q0; S0 += q0 * xs;
        den1 += q1; S1 += q1 * xs;
    }
    S0 /= (den0 + EPSF);
    S1 /= (den1 + EPSF);
    float h1[64];
#pragma unroll
    for (int d = 0; d < 64; d++) {
        float v = sW1[d] * (d < 32 ? S0 : S1) + sb1[d];
        h1[d] = v > 0.f ? v : fexp(v) - 1.f;   // ELU
    }
    float a_s = 0.f, a_d = 0.f;
    float acc[32];
#pragma unroll 4
    for (int j = 0; j < 32; j++) {
        float a = 0.f;
#pragma unroll
        for (int d = 0; d < 64; d++) a += h1[d] * sW2[d * 32 + j];
        acc[j] = a;
        a_s += a * sas[j];
        a_d += a * sad[j];
    }
    float4* op = (float4*)(h2s + (size_t)idx * 32);
#pragma unroll
    for (int q = 0; q < 8; q++)
        op[q] = make_float4(acc[4 * q], acc[4 * q + 1], acc[4 * q + 2], acc[4 * q + 3]);
    as2[idx] = a_s;
    ad2[idx] = a_d;
}

// Layer-2 gather-softmax aggregation -> enc[t][n][32].
// 32 lanes per (t,dst) node. Two-phase tiles of 32 edges (LDS-staged q/off).
__global__ __launch_bounds__(256) void k_l2(
        const int* __restrict__ row, const unsigned short* __restrict__ csr,
        const float* __restrict__ as2, const float* __restrict__ ad2,
        const float* __restrict__ h2s, const float* __restrict__ b2,
        float* __restrict__ enc) {
    __shared__ float2 qoff[8][32];     // [group][e] = {q, as_int(src*32)}
    int tid = threadIdx.x;
    int g = tid >> 5, lane = tid & 31;
    int b = blockIdx.x;
    int t = b & 7, chunk = b >> 3;     // 2500 chunks * 8 nodes = NN
    int n = chunk * 8 + g;
    int pair = t * NN + n;
    int base = t * NN;
    const float* hb = h2s + (size_t)base * 32;
    float adn = ad2[pair];
    float vs = as2[pair] + adn; vs = vs > 0.f ? vs : 0.2f * vs;
    float qs = fexp(vs);
    float num = qs * hb[(size_t)n * 32 + lane];
    float den_part = 0.f;
    int rs = row[t * (NN + 1) + n], re = row[t * (NN + 1) + n + 1];
    const unsigned short* cp = csr + (size_t)t * NE;
    for (int i0 = rs; i0 < re; i0 += 32) {
        int cnt = re - i0; if (cnt > 32) cnt = 32;
        float q = 0.f;
        if (lane < cnt) {
            int s = cp[i0 + lane];                   // coalesced 64B
            float a = as2[base + s];                 // 1 gather per edge total
            float u = a + adn; u = u > 0.f ? u : 0.2f * u;
            q = fexp(u);
            qoff[g][lane] = make_float2(q, __int_as_float(s * 32));
        }
        den_part += q;
        __builtin_amdgcn_wave_barrier();             // order LDS write -> read
        int e = 0;
        for (; e + 4 <= cnt; e += 4) {
            float4 p0 = *(const float4*)&qoff[g][e];
            float4 p1 = *(const float4*)&qoff[g][e + 2];
            num += p0.x * hb[__float_as_int(p0.y) + lane];
            num += p0.z * hb[__float_as_int(p0.w) + lane];
            num += p1.x * hb[__float_as_int(p1.y) + lane];
            num += p1.z * hb[__float_as_int(p1.w) + lane];
        }
        for (; e + 2 <= cnt; e += 2) {
            float4 p0 = *(const float4*)&qoff[g][e];
            num += p0.x * hb[__float_as_int(p0.y) + lane];
            num += p0.z * hb[__float_as_int(p0.w) + lane];
        }
        if (e < cnt) {
            float2 p = qoff[g][e];
            num += p.x * hb[__float_as_int(p.y) + lane];
        }
        __builtin_amdgcn_wave_barrier();             // reads done before next tile
    }
    float den = den_part;
#pragma unroll
    for (int off = 16; off > 0; off >>= 1) den += __shfl_xor(den, off, 32);
    den += qs;
    float ev = num / (den + EPSF) + b2[lane];
    ev = ev > 0.f ? ev : fexp(ev) - 1.f;   // ELU
    enc[(size_t)pair * 32 + lane] = ev;
}

// GRU over T + FC head. G=2, merged e/h float4 LDS buffer, ALL 8 enc loads
// issued up front (16 VGPR) + fully unrolled t-loop: no global-load latency
// inside the recurrence. Wave-local groups: wave_barrier only.
__global__ __launch_bounds__(256) void k_gru(
        const float* __restrict__ enc, const float* __restrict__ wp,
        const float* __restrict__ bih, const float* __restrict__ bhh,
        const float* __restrict__ fcw, const float* __restrict__ fcb,
        float* __restrict__ out) {
    __shared__ float4 wpA[1024];       // [k*32+j] {wi_r, wi_z, wi_n, wh_r}
    __shared__ float2 wpB[1024];       // [k*32+j] {wh_z, wh_n}
    __shared__ float sbih[96], sbhh[96], sfw[32];
    __shared__ float4 buf[8][32];      // [group][k] = {e0, e1, h0, h1}
    int tid = threadIdx.x;
    const float4* wpAg = (const float4*)wp;
    const float2* wpBg = (const float2*)(wp + 4096);
    for (int i = tid; i < 1024; i += 256) { wpA[i] = wpAg[i]; wpB[i] = wpBg[i]; }
    if (tid < 96) { sbih[tid] = bih[tid]; sbhh[tid] = bhh[tid]; }
    if (tid < 32) sfw[tid] = fcw[tid];
    int g = tid >> 5, lane = tid & 31;
    int n0 = blockIdx.x * 16 + g * 2;  // 1250 blocks * 16 nodes = 20000
    float h0 = 0.f, h1v = 0.f;
    ((float2*)&buf[g][lane])[1] = make_float2(0.f, 0.f);   // h half
    // issue all 8 timesteps' enc loads up front (independent, all in flight)
    const float* ep0 = enc + (size_t)n0 * 32 + lane;
    float2 ev[TT];
#pragma unroll
    for (int t = 0; t < TT; t++) {
        const float* ep = ep0 + (size_t)t * NN * 32;
        ev[t] = make_float2(ep[0], ep[32]);
    }
    __syncthreads();                   // weight staging is cross-wave
    float bi_r = sbih[lane], bi_z = sbih[32 + lane], bi_n = sbih[64 + lane];
    float bh_r = sbhh[lane], bh_z = sbhh[32 + lane], bh_n = sbhh[64 + lane];
#pragma unroll
    for (int t = 0; t < TT; t++) {
        ((float2*)&buf[g][lane])[0] = ev[t];               // e half
        __builtin_amdgcn_wave_barrier();
        float ir0 = bi_r, ir1 = bi_r, iz0 = bi_z, iz1 = bi_z;
        float in0 = bi_n, in1 = bi_n;
        float hr0 = bh_r, hr1 = bh_r, hz0 = bh_z, hz1 = bh_z;
        float hn0 = bh_n, hn1 = bh_n;
#pragma unroll 16
        for (int k = 0; k < 32; k++) {
            float4 wa = wpA[k * 32 + lane];
            float2 wb = wpB[k * 32 + lane];
            float4 eh = buf[g][k];     // {e0, e1, h0, h1} one b128 broadcast
            ir0 += wa.x * eh.x; ir1 += wa.x * eh.y;
            iz0 += wa.y * eh.x; iz1 += wa.y * eh.y;
            in0 += wa.z * eh.x; in1 += wa.z * eh.y;
            hr0 += wa.w * eh.z; hr1 += wa.w * eh.w;
            hz0 += wb.x * eh.z; hz1 += wb.x * eh.w;
            hn0 += wb.y * eh.z; hn1 += wb.y * eh.w;
        }
        __builtin_amdgcn_wave_barrier();   // reads done before overwrite
        float r0 = fsigmoid(ir0 + hr0), r1 = fsigmoid(ir1 + hr1);
        float z0 = fsigmoid(iz0 + hz0), z1 = fsigmoid(iz1 + hz1);
        float nn0 = ftanh(in0 + r0 * hn0), nn1 = ftanh(in1 + r1 * hn1);
        h0  = (1.f - z0) * nn0 + z0 * h0;
        h1v = (1.f - z1) * nn1 + z1 * h1v;
        ((float2*)&buf[g][lane])[1] = make_float2(h0, h1v);  // h half
        __builtin_amdgcn_wave_barrier();
    }
    float fw = sfw[lane], fb = fcb[0];
    float v0 = h0 * fw, v1 = h1v * fw;
#pragma unroll
    for (int off = 16; off > 0; off >>= 1) {
        v0 += __shfl_down(v0, off, 32);
        v1 += __shfl_down(v1, off, 32);
    }
    if (lane == 0) {
        out[n0 + 0] = v0 + fb;
        out[n0 + 1] = v1 + fb;
    }
}

extern "C" void kernel_launch(void* const* d_in, const int* in_sizes, int n_in,
                              void* d_out, int out_size, void* d_ws, size_t ws_size,
                              hipStream_t stream) {
    const float* x    = (const float*)d_in[0];
    const int*   ei   = (const int*)d_in[1];
    const float* W1   = (const float*)d_in[2];
    const float* as1  = (const float*)d_in[3];
    const float* ad1  = (const float*)d_in[4];
    const float* b1   = (const float*)d_in[5];
    const float* W2   = (const float*)d_in[6];
    const float* as2w = (const float*)d_in[7];
    const float* ad2w = (const float*)d_in[8];
    const float* b2   = (const float*)d_in[9];
    const float* wih  = (const float*)d_in[10];
    const float* whh  = (const float*)d_in[11];
    const float* bih  = (const float*)d_in[12];
    const float* bhh  = (const float*)d_in[13];
    const float* fcw  = (const float*)d_in[14];
    const float* fcb  = (const float*)d_in[15];
    float* ws  = (float*)d_ws;
    float* out = (float*)d_out;

    int*            rt   = (int*)(ws + OFF_RT);
    int*            rowp = (int*)(ws + OFF_ROW);
    unsigned short* csr  = (unsigned short*)(ws + OFF_CSR);
    int*            bh   = (int*)(ws + OFF_H2S);      // aliased, dead before k_l1
    unsigned*       bkt  = (unsigned*)(ws + OFF_ENC); // aliased, dead before k_l2
    float*          wp   = ws + OFF_WP;

    k_bhist<<<TT * NCH, 256, 0, stream>>>(ei, bh, wih, whh, wp);
    k_bscan1<<<TT * NR, 256, 0, stream>>>(bh, rt);
    k_bplace<<<TT * NCH, 256, 0, stream>>>(ei, bh, rt, bkt);
    k_csr<<<TT * NR, 256, 0, stream>>>(bkt, rt, rowp, csr);

    k_l1<<<TT * ((NN + 255) / 256), 256, 0, stream>>>(x, rowp, csr, as1, ad1,
                                              W1, b1, W2, as2w, ad2w,
                                              ws + OFF_H2S, ws + OFF_AS2, ws + OFF_AD2);

    k_l2<<<TT * (NN / 8), 256, 0, stream>>>(rowp, csr, ws + OFF_AS2, ws + OFF_AD2,
                                            ws + OFF_H2S, b2, ws + OFF_ENC);

    k_gru<<<NN / 16, 256, 0, stream>>>(ws + OFF_ENC, wp, bih, bhh,
                                       fcw, fcb, out);
}

// Round 20
// 253.311 us; speedup vs baseline: 1.0103x; 1.0103x over previous
//
#include <hip/hip_runtime.h>
#include <cmath>

#define NN 20000
#define NE 320000
#define TT 8
#define EPSF 1e-16f
#define NR 32          // dst ranges per timestep
#define RSZ 625        // NN / NR
#define NCH 1250       // edge chunks per timestep (256 edges each)

// ---- workspace layout (4-byte word offsets) ----
#define OFF_RT  0                        // int [T][NR] range totals (1024 pad)
#define OFF_ROW 1024                     // int [T][N+1] CSR row starts
#define OFF_CSR (OFF_ROW + TT*(NN+1))    // ushort[T][NE]
#define OFF_H2S (OFF_CSR + TT*NE/2)      // float [T][N][32]  (aliases bh)
#define OFF_AS2 (OFF_H2S + TT*NN*32)     // float [T][N]
#define OFF_AD2 (OFF_AS2 + TT*NN)        // float [T][N]
#define OFF_ENC (OFF_AD2 + TT*NN)        // float [T][N][32]  (aliases bkt)
#define OFF_WP  (OFF_ENC + TT*NN*32)     // packed GRU weights
#define WS_WORDS (OFF_WP + 6144)

__device__ __forceinline__ float fexp(float x) { return __expf(x); }
__device__ __forceinline__ float fsigmoid(float x) { return 1.f / (1.f + __expf(-x)); }
__device__ __forceinline__ float ftanh(float x) {
    float ax = fabsf(x);
    float e2 = __expf(-2.f * ax);
    float th = (1.f - e2) / (1.f + e2);
    return copysignf(th, x);
}

// Stage 1: per-(t,chunk) histogram over NR dst ranges. 1 edge per thread.
// Blocks 0..3 additionally pack the GRU weights into wp:
//   wp[0..4096)  float4 {wi_r, wi_z, wi_n, wh_r}[k*32+j]
//   wp[4096..)   float2 {wh_z, wh_n}[k*32+j]
__global__ __launch_bounds__(256) void k_bhist(const int* __restrict__ ei,
                                               int* __restrict__ bh,
                                               const float* __restrict__ wih,
                                               const float* __restrict__ whh,
                                               float* __restrict__ wp) {
    int b = blockIdx.x;
    int t = b & 7, c = b >> 3;
    __shared__ int cnt[NR];
    int tid = threadIdx.x;
    if (b < 4) {                       // fold k_wpack: 4*256 = 1024 entries
        int i = b * 256 + tid;
        int k = i >> 5, j = i & 31;
        ((float4*)wp)[i] = make_float4(wih[j * 32 + k], wih[(32 + j) * 32 + k],
                                       wih[(64 + j) * 32 + k], whh[j * 32 + k]);
        ((float2*)(wp + 4096))[i] = make_float2(whh[(32 + j) * 32 + k],
                                                whh[(64 + j) * 32 + k]);
    }
    if (tid < NR) cnt[tid] = 0;
    __syncthreads();
    int e = c * 256 + tid;
    int dst = ei[(size_t)t * 2 * NE + NE + e];
    int r = dst / RSZ;
    atomicAdd(&cnt[r], 1);
    __syncthreads();
    if (tid < NR) bh[(t * NCH + c) * NR + tid] = cnt[tid];
}

// Stage 2: per-(t,r) exclusive scan over NCH chunk counts (in place) + totals.
__global__ __launch_bounds__(256) void k_bscan1(int* __restrict__ bh,
                                                int* __restrict__ rt) {
    int b = blockIdx.x;                // 256 = (t,r)
    int t = b & 7, r = b >> 3;
    __shared__ int sums[256];
    int tid = threadIdx.x;
    int c0 = tid * 5, c1 = c0 + 5; if (c1 > NCH) c1 = NCH; if (c0 > NCH) c0 = NCH;
    int v[5]; int s = 0;
    for (int c = c0, k = 0; c < c1; c++, k++) { v[k] = bh[(t * NCH + c) * NR + r]; s += v[k]; }
    sums[tid] = s;
    __syncthreads();
    if (tid == 0) {
        int acc = 0;
        for (int i = 0; i < 256; i++) { int x = sums[i]; sums[i] = acc; acc += x; }
        rt[t * NR + r] = acc;          // bucket total
    }
    __syncthreads();
    int acc = sums[tid];
    for (int c = c0, k = 0; c < c1; c++, k++) { bh[(t * NCH + c) * NR + r] = acc; acc += v[k]; }
}

// Stage 3: place each edge into its range bucket. bkt entry: (src<<10)|dstlocal.
__global__ __launch_bounds__(256) void k_bplace(const int* __restrict__ ei,
                                                const int* __restrict__ bh,
                                                const int* __restrict__ rt,
                                                unsigned* __restrict__ bkt) {
    int b = blockIdx.x;
    int t = b & 7, c = b >> 3;
    __shared__ int cnt[NR], base[NR], rbs[NR];
    int tid = threadIdx.x;
    if (tid == 0) {
        int acc = 0;
        for (int r = 0; r < NR; r++) { rbs[r] = acc; acc += rt[t * NR + r]; }
    }
    if (tid < NR) {
        cnt[tid] = 0;
        base[tid] = bh[(t * NCH + c) * NR + tid];
    }
    __syncthreads();
    int e = c * 256 + tid;
    int src = ei[(size_t)t * 2 * NE + e];
    int dst = ei[(size_t)t * 2 * NE + NE + e];
    int r = dst / RSZ;
    int pos = atomicAdd(&cnt[r], 1);
    bkt[(size_t)t * NE + rbs[r] + base[r] + pos] =
        ((unsigned)src << 10) | (unsigned)(dst - r * RSZ);
}

// Stage 4: per-(t,r) bucket -> per-dst CSR. Each block owns ~10K edges.
__global__ __launch_bounds__(256) void k_csr(const unsigned* __restrict__ bkt,
                                             const int* __restrict__ rt,
                                             int* __restrict__ row,
                                             unsigned short* __restrict__ csr) {
    int b = blockIdx.x;                // 256 = (t,r)
    int t = b & 7, r = b >> 3;
    __shared__ int segs[2];
    __shared__ int deg[RSZ];
    __shared__ int cur[RSZ];
    __shared__ int sums[256];
    int tid = threadIdx.x;
    if (tid == 0) {
        int acc = 0, s0 = 0;
        for (int i = 0; i < NR; i++) { if (i == r) s0 = acc; acc += rt[t * NR + i]; }
        segs[0] = s0;
        segs[1] = (r == NR - 1) ? acc : s0 + rt[t * NR + r];
    }
    for (int i = tid; i < RSZ; i += 256) deg[i] = 0;
    __syncthreads();
    int seg0 = segs[0], seg1 = segs[1];
    int lo = r * RSZ;
    const unsigned* bp = bkt + (size_t)t * NE;
    for (int i = seg0 + tid; i < seg1; i += 256)
        atomicAdd(&deg[bp[i] & 1023], 1);
    __syncthreads();
    int c0 = tid * 3, c1 = c0 + 3; if (c1 > RSZ) c1 = RSZ; if (c0 > RSZ) c0 = RSZ;
    int v[3]; int s = 0;
    for (int i = c0, k = 0; i < c1; i++, k++) { v[k] = deg[i]; s += v[k]; }
    sums[tid] = s;
    __syncthreads();
    if (tid == 0) {
        int acc = 0;
        for (int i = 0; i < 256; i++) { int x = sums[i]; sums[i] = acc; acc += x; }
    }
    __syncthreads();
    int acc = sums[tid];
    for (int i = c0, k = 0; i < c1; i++, k++) {
        int off = seg0 + acc;
        row[t * (NN + 1) + lo + i] = off;
        cur[i] = off;
        acc += v[k];
    }
    if (r == NR - 1 && tid == 0) row[t * (NN + 1) + NN] = seg1;  // == NE
    __syncthreads();
    unsigned short* cp = csr + (size_t)t * NE;
    for (int i = seg0 + tid; i < seg1; i += 256) {
        unsigned pk = bp[i];
        int pos = atomicAdd(&cur[pk & 1023], 1);
        cp[pos] = (unsigned short)(pk >> 10);
    }
}

// Fused: layer-1 scalar-softmax gather + h1 -> h2 matvec + layer-2 attn scalars
__global__ __launch_bounds__(256) void k_l1(
        const float* __restrict__ x, const int* __restrict__ row,
        const unsigned short* __restrict__ csr,
        const float* __restrict__ as1, const float* __restrict__ ad1,
        const float* __restrict__ W1, const float* __restrict__ b1,
        const float* __restrict__ W2,
        const float* __restrict__ as2w, const float* __restrict__ ad2w,
        float* __restrict__ h2s, float* __restrict__ as2, float* __restrict__ ad2) {
    __shared__ float sW2[64 * 32];
    __shared__ float sW1[64], sb1[64], sas[32], sad[32], sc[4];
    int tid = threadIdx.x;
    for (int i = tid; i < 64 * 32; i += 256) sW2[i] = W2[i];
    if (tid < 64) { sW1[tid] = W1[tid]; sb1[tid] = b1[tid]; }
    if (tid < 32) { sas[tid] = as2w[tid]; sad[tid] = ad2w[tid]; }
    if (tid < 4) {                      // sc = {cs1_h0, cs1_h1, cd1_h0, cd1_h1}
        int hd = tid & 1;
        const float* att = (tid < 2) ? as1 : ad1;
        float s = 0.f;
        for (int k = 0; k < 32; k++) s += W1[hd * 32 + k] * att[hd * 32 + k];
        sc[tid] = s;
    }
    __syncthreads();
    int b = blockIdx.x;
    int t = b & 7, chunk = b >> 3;      // 79 chunks per t
    int n = chunk * 256 + tid;
    if (n >= NN) return;
    int idx = t * NN + n;
    float cs0 = sc[0], cs1 = sc[1], cd0 = sc[2], cd1 = sc[3];
    float xd = x[idx];
    // self-loop term (src == dst == n)
    float v0 = xd * (cs0 + cd0); v0 = v0 > 0.f ? v0 : 0.2f * v0; float ex0 = fexp(v0);
    float v1 = xd * (cs1 + cd1); v1 = v1 > 0.f ? v1 : 0.2f * v1; float ex1 = fexp(v1);
    float den0 = ex0, den1 = ex1, S0 = ex0 * xd, S1 = ex1 * xd;
    int rs = row[t * (NN + 1) + n], re = row[t * (NN + 1) + n + 1];
    const unsigned short* cp = csr + (size_t)t * NE;
    const float* xp = x + t * NN;
    int i = rs;
    for (; i < re && (i & 3); i++) {
        int src = cp[i];
        float xs = xp[src];
        float u0 = xs * cs0 + xd * cd0; u0 = u0 > 0.f ? u0 : 0.2f * u0; float q0 = fexp(u0);
        float u1 = xs * cs1 + xd * cd1; u1 = u1 > 0.f ? u1 : 0.2f * u1; float q1 = fexp(u1);
        den0 += q0; S0 += q0 * xs;
        den1 += q1; S1 += q1 * xs;
    }
    for (; i + 4 <= re; i += 4) {
        ushort4 s4 = *(const ushort4*)(cp + i);    // 8B aligned: i%4==0
        float xA = xp[s4.x], xB = xp[s4.y], xC = xp[s4.z], xD = xp[s4.w];
        float uA0 = xA * cs0 + xd * cd0; uA0 = uA0 > 0.f ? uA0 : 0.2f * uA0; float qA0 = fexp(uA0);
        float uB0 = xB * cs0 + xd * cd0; uB0 = uB0 > 0.f ? uB0 : 0.2f * uB0; float qB0 = fexp(uB0);
        float uC0 = xC * cs0 + xd * cd0; uC0 = uC0 > 0.f ? uC0 : 0.2f * uC0; float qC0 = fexp(uC0);
        float uD0 = xD * cs0 + xd * cd0; uD0 = uD0 > 0.f ? uD0 : 0.2f * uD0; float qD0 = fexp(uD0);
        float uA1 = xA * cs1 + xd * cd1; uA1 = uA1 > 0.f ? uA1 : 0.2f * uA1; float qA1 = fexp(uA1);
        float uB1 = xB * cs1 + xd * cd1; uB1 = uB1 > 0.f ? uB1 : 0.2f * uB1; float qB1 = fexp(uB1);
        float uC1 = xC * cs1 + xd * cd1; uC1 = uC1 > 0.f ? uC1 : 0.2f * uC1; float qC1 = fexp(uC1);
        float uD1 = xD * cs1 + xd * cd1; uD1 = uD1 > 0.f ? uD1 : 0.2f * uD1; float qD1 = fexp(uD1);
        den0 += (qA0 + qB0) + (qC0 + qD0);
        S0 += qA0 * xA + qB0 * xB + qC0 * xC + qD0 * xD;
        den1 += (qA1 + qB1) + (qC1 + qD1);
        S1 += qA1 * xA + qB1 * xB + qC1 * xC + qD1 * xD;
    }
    for (; i < re; i++) {
        int src = cp[i];
        float xs = xp[src];
        float u0 = xs * cs0 + xd * cd0; u0 = u0 > 0.f ? u0 : 0.2f * u0; float q0 = fexp(u0);
        float u1 = xs * cs1 + xd * cd1; u1 = u1 > 0.f ? u1 : 0.2f * u1; float q1 = fexp(u1);
        den0 += q0; S0 += q0 * xs;
        den1 += q1; S1 += q1 * xs;
    }
    S0 /= (den0 + EPSF);
    S1 /= (den1 + EPSF);
    float h1[64];
#pragma unroll
    for (int d = 0; d < 64; d++) {
        float v = sW1[d] * (d < 32 ? S0 : S1) + sb1[d];
        h1[d] = v > 0.f ? v : fexp(v) - 1.f;   // ELU
    }
    float a_s = 0.f, a_d = 0.f;
    float acc[32];
#pragma unroll 4
    for (int j = 0; j < 32; j++) {
        float a = 0.f;
#pragma unroll
        for (int d = 0; d < 64; d++) a += h1[d] * sW2[d * 32 + j];
        acc[j] = a;
        a_s += a * sas[j];
        a_d += a * sad[j];
    }
    float4* op = (float4*)(h2s + (size_t)idx * 32);
#pragma unroll
    for (int q = 0; q < 8; q++)
        op[q] = make_float4(acc[4 * q], acc[4 * q + 1], acc[4 * q + 2], acc[4 * q + 3]);
    as2[idx] = a_s;
    ad2[idx] = a_d;
}

// Layer-2 gather-softmax aggregation -> enc[t][n][32].
// 32 lanes per (t,dst) node. Two-phase tiles of 32 edges (LDS-staged q/off).
__global__ __launch_bounds__(256) void k_l2(
        const int* __restrict__ row, const unsigned short* __restrict__ csr,
        const float* __restrict__ as2, const float* __restrict__ ad2,
        const float* __restrict__ h2s, const float* __restrict__ b2,
        float* __restrict__ enc) {
    __shared__ float2 qoff[8][32];     // [group][e] = {q, as_int(src*32)}
    int tid = threadIdx.x;
    int g = tid >> 5, lane = tid & 31;
    int b = blockIdx.x;
    int t = b & 7, chunk = b >> 3;     // 2500 chunks * 8 nodes = NN
    int n = chunk * 8 + g;
    int pair = t * NN + n;
    int base = t * NN;
    const float* hb = h2s + (size_t)base * 32;
    float adn = ad2[pair];
    float vs = as2[pair] + adn; vs = vs > 0.f ? vs : 0.2f * vs;
    float qs = fexp(vs);
    float num = qs * hb[(size_t)n * 32 + lane];
    float den_part = 0.f;
    int rs = row[t * (NN + 1) + n], re = row[t * (NN + 1) + n + 1];
    const unsigned short* cp = csr + (size_t)t * NE;
    for (int i0 = rs; i0 < re; i0 += 32) {
        int cnt = re - i0; if (cnt > 32) cnt = 32;
        float q = 0.f;
        if (lane < cnt) {
            int s = cp[i0 + lane];                   // coalesced 64B
            float a = as2[base + s];                 // 1 gather per edge total
            float u = a + adn; u = u > 0.f ? u : 0.2f * u;
            q = fexp(u);
            qoff[g][lane] = make_float2(q, __int_as_float(s * 32));
        }
        den_part += q;
        __builtin_amdgcn_wave_barrier();             // order LDS write -> read
        int e = 0;
        for (; e + 4 <= cnt; e += 4) {
            float4 p0 = *(const float4*)&qoff[g][e];
            float4 p1 = *(const float4*)&qoff[g][e + 2];
            num += p0.x * hb[__float_as_int(p0.y) + lane];
            num += p0.z * hb[__float_as_int(p0.w) + lane];
            num += p1.x * hb[__float_as_int(p1.y) + lane];
            num += p1.z * hb[__float_as_int(p1.w) + lane];
        }
        for (; e + 2 <= cnt; e += 2) {
            float4 p0 = *(const float4*)&qoff[g][e];
            num += p0.x * hb[__float_as_int(p0.y) + lane];
            num += p0.z * hb[__float_as_int(p0.w) + lane];
        }
        if (e < cnt) {
            float2 p = qoff[g][e];
            num += p.x * hb[__float_as_int(p.y) + lane];
        }
        __builtin_amdgcn_wave_barrier();             // reads done before next tile
    }
    float den = den_part;
#pragma unroll
    for (int off = 16; off > 0; off >>= 1) den += __shfl_xor(den, off, 32);
    den += qs;
    float ev = num / (den + EPSF) + b2[lane];
    ev = ev > 0.f ? ev : fexp(ev) - 1.f;   // ELU
    enc[(size_t)pair * 32 + lane] = ev;
}

// GRU over T + FC head — R18 config (session best: 47.5 us). G=2, merged e/h
// float4 LDS buffer {e0,e1,h0,h1} (3 LDS reads/k), rolling single prefetch.
// Wave-local groups: wave_barrier only in t-loop.
__global__ __launch_bounds__(256) void k_gru(
        const float* __restrict__ enc, const float* __restrict__ wp,
        const float* __restrict__ bih, const float* __restrict__ bhh,
        const float* __restrict__ fcw, const float* __restrict__ fcb,
        float* __restrict__ out) {
    __shared__ float4 wpA[1024];       // [k*32+j] {wi_r, wi_z, wi_n, wh_r}
    __shared__ float2 wpB[1024];       // [k*32+j] {wh_z, wh_n}
    __shared__ float sbih[96], sbhh[96], sfw[32];
    __shared__ float4 buf[8][32];      // [group][k] = {e0, e1, h0, h1}
    int tid = threadIdx.x;
    const float4* wpAg = (const float4*)wp;
    const float2* wpBg = (const float2*)(wp + 4096);
    for (int i = tid; i < 1024; i += 256) { wpA[i] = wpAg[i]; wpB[i] = wpBg[i]; }
    if (tid < 96) { sbih[tid] = bih[tid]; sbhh[tid] = bhh[tid]; }
    if (tid < 32) sfw[tid] = fcw[tid];
    int g = tid >> 5, lane = tid & 31;
    int n0 = blockIdx.x * 16 + g * 2;  // 1250 blocks * 16 nodes = 20000
    float h0 = 0.f, h1v = 0.f;
    ((float2*)&buf[g][lane])[1] = make_float2(0.f, 0.f);   // h half
    __syncthreads();                   // weight staging is cross-wave
    float bi_r = sbih[lane], bi_z = sbih[32 + lane], bi_n = sbih[64 + lane];
    float bh_r = sbhh[lane], bh_z = sbhh[32 + lane], bh_n = sbhh[64 + lane];
    const float* ep0 = enc + (size_t)n0 * 32 + lane;
    float2 ecur = make_float2(ep0[0], ep0[32]);
    for (int t = 0; t < TT; t++) {
        ((float2*)&buf[g][lane])[0] = ecur;                // e half
        __builtin_amdgcn_wave_barrier();
        if (t < TT - 1) {              // prefetch next t over the k-loop
            const float* ep = ep0 + (size_t)(t + 1) * NN * 32;
            ecur = make_float2(ep[0], ep[32]);
        }
        float ir0 = bi_r, ir1 = bi_r, iz0 = bi_z, iz1 = bi_z;
        float in0 = bi_n, in1 = bi_n;
        float hr0 = bh_r, hr1 = bh_r, hz0 = bh_z, hz1 = bh_z;
        float hn0 = bh_n, hn1 = bh_n;
#pragma unroll 16
        for (int k = 0; k < 32; k++) {
            float4 wa = wpA[k * 32 + lane];
            float2 wb = wpB[k * 32 + lane];
            float4 eh = buf[g][k];     // {e0, e1, h0, h1} one b128 broadcast
            ir0 += wa.x * eh.x; ir1 += wa.x * eh.y;
            iz0 += wa.y * eh.x; iz1 += wa.y * eh.y;
            in0 += wa.z * eh.x; in1 += wa.z * eh.y;
            hr0 += wa.w * eh.z; hr1 += wa.w * eh.w;
            hz0 += wb.x * eh.z; hz1 += wb.x * eh.w;
            hn0 += wb.y * eh.z; hn1 += wb.y * eh.w;
        }
        __builtin_amdgcn_wave_barrier();   // reads done before overwrite
        float r0 = fsigmoid(ir0 + hr0), r1 = fsigmoid(ir1 + hr1);
        float z0 = fsigmoid(iz0 + hz0), z1 = fsigmoid(iz1 + hz1);
        float nn0 = ftanh(in0 + r0 * hn0), nn1 = ftanh(in1 + r1 * hn1);
        h0  = (1.f - z0) * nn0 + z0 * h0;
        h1v = (1.f - z1) * nn1 + z1 * h1v;
        ((float2*)&buf[g][lane])[1] = make_float2(h0, h1v);  // h half
        __builtin_amdgcn_wave_barrier();
    }
    float fw = sfw[lane], fb = fcb[0];
    float v0 = h0 * fw, v1 = h1v * fw;
#pragma unroll
    for (int off = 16; off > 0; off >>= 1) {
        v0 += __shfl_down(v0, off, 32);
        v1 += __shfl_down(v1, off, 32);
    }
    if (lane == 0) {
        out[n0 + 0] = v0 + fb;
        out[n0 + 1] = v1 + fb;
    }
}

extern "C" void kernel_launch(void* const* d_in, const int* in_sizes, int n_in,
                              void* d_out, int out_size, void* d_ws, size_t ws_size,
                              hipStream_t stream) {
    const float* x    = (const float*)d_in[0];
    const int*   ei   = (const int*)d_in[1];
    const float* W1   = (const float*)d_in[2];
    const float* as1  = (const float*)d_in[3];
    const float* ad1  = (const float*)d_in[4];
    const float* b1   = (const float*)d_in[5];
    const float* W2   = (const float*)d_in[6];
    const float* as2w = (const float*)d_in[7];
    const float* ad2w = (const float*)d_in[8];
    const float* b2   = (const float*)d_in[9];
    const float* wih  = (const float*)d_in[10];
    const float* whh  = (const float*)d_in[11];
    const float* bih  = (const float*)d_in[12];
    const float* bhh  = (const float*)d_in[13];
    const float* fcw  = (const float*)d_in[14];
    const float* fcb  = (const float*)d_in[15];
    float* ws  = (float*)d_ws;
    float* out = (float*)d_out;

    int*            rt   = (int*)(ws + OFF_RT);
    int*            rowp = (int*)(ws + OFF_ROW);
    unsigned short* csr  = (unsigned short*)(ws + OFF_CSR);
    int*            bh   = (int*)(ws + OFF_H2S);      // aliased, dead before k_l1
    unsigned*       bkt  = (unsigned*)(ws + OFF_ENC); // aliased, dead before k_l2
    float*          wp   = ws + OFF_WP;

    k_bhist<<<TT * NCH, 256, 0, stream>>>(ei, bh, wih, whh, wp);
    k_bscan1<<<TT * NR, 256, 0, stream>>>(bh, rt);
    k_bplace<<<TT * NCH, 256, 0, stream>>>(ei, bh, rt, bkt);
    k_csr<<<TT * NR, 256, 0, stream>>>(bkt, rt, rowp, csr);

    k_l1<<<TT * ((NN + 255) / 256), 256, 0, stream>>>(x, rowp, csr, as1, ad1,
                                              W1, b1, W2, as2w, ad2w,
                                              ws + OFF_H2S, ws + OFF_AS2, ws + OFF_AD2);

    k_l2<<<TT * (NN / 8), 256, 0, stream>>>(rowp, csr, ws + OFF_AS2, ws + OFF_AD2,
                                            ws + OFF_H2S, b2, ws + OFF_ENC);

    k_gru<<<NN / 16, 256, 0, stream>>>(ws + OFF_ENC, wp, bih, bhh,
                                       fcw, fcb, out);
}